// Round 8
// baseline (723.523 us; speedup 1.0000x reference)
//
#include <hip/hip_runtime.h>
#include <hip/hip_fp16.h>

typedef __half f16;
typedef _Float16 half8 __attribute__((ext_vector_type(8)));
typedef float floatx4 __attribute__((ext_vector_type(4)));

#define NN   100000   // nodes
#define NE   1600000  // edges
#define CIN  256
#define CH   128
#define COUT 64
#define NB   64

#define NBUK 128      // scan buckets
#define NPB  782      // nodes per bucket (128*782 = 100096 >= NN)

// ---------------- diagnostics ----------------
__global__ void k_sentinel(float* __restrict__ out, int n, float val) {
    int i = blockIdx.x * 256 + threadIdx.x;
    if (i < n) out[i] = val;
}

// ---------------- init: pool/cnt/deg zero ----------------
__global__ void k_init(float* __restrict__ pool, float* __restrict__ cnt,
                       int* __restrict__ deg) {
    int i = blockIdx.x * 256 + threadIdx.x;
    if (i < NB * CH) pool[i] = 0.0f;
    if (i < NB) cnt[i] = 0.0f;
    if (i < NN) deg[i] = 0;
}

// ---------------- CSR build, counting sort ----------------
// deg histogram: 1.6M atomics over 100K addresses (mean 16/addr, low contention)
__global__ __launch_bounds__(256) void k_deg(const int* __restrict__ dst,
                                             int* __restrict__ deg) {
    int i = blockIdx.x * 256 + threadIdx.x;     // indexes int4
    if (i < NE / 4) {
        int4 d = ((const int4*)dst)[i];
        atomicAdd(&deg[d.x], 1);
        atomicAdd(&deg[d.y], 1);
        atomicAdd(&deg[d.z], 1);
        atomicAdd(&deg[d.w], 1);
    }
}

// per-bucket degree sums
__global__ __launch_bounds__(256) void k_bsum(const int* __restrict__ deg,
                                              int* __restrict__ bsum) {
    __shared__ int red[4];
    const int b = blockIdx.x, tid = threadIdx.x;
    const int nbase = b * NPB;
    const int nend = (nbase + NPB < NN) ? nbase + NPB : NN;
    int s = 0;
    for (int i = nbase + tid; i < nend; i += 256) s += deg[i];
#pragma unroll
    for (int off = 32; off; off >>= 1) s += __shfl_down(s, off);
    if ((tid & 63) == 0) red[tid >> 6] = s;
    __syncthreads();
    if (tid == 0) bsum[b] = red[0] + red[1] + red[2] + red[3];
}

// exclusive scan of bucket sums
__global__ void k_scanb(const int* __restrict__ bsum, int* __restrict__ barr,
                        int* __restrict__ rowptr) {
    int lane = threadIdx.x;   // 64 threads
    int carry = 0;
    for (int c0 = 0; c0 < NBUK; c0 += 64) {
        int idx = c0 + lane;
        int orig = bsum[idx];
        int v = orig;
#pragma unroll
        for (int off = 1; off < 64; off <<= 1) {
            int t = __shfl_up(v, off);
            if (lane >= off) v += t;
        }
        barr[idx] = v - orig + carry;
        carry += __shfl(v, 63);
    }
    if (lane == 0) rowptr[NN] = NE;
}

// per-bucket exclusive scan -> rowptr, cursor, dinv
__global__ __launch_bounds__(256) void k_brow(const int* __restrict__ deg,
                                              const int* __restrict__ barr,
                                              int* __restrict__ rowptr,
                                              int* __restrict__ cursor,
                                              float* __restrict__ dinv) {
    __shared__ int hist[NPB];
    const int b = blockIdx.x, tid = threadIdx.x;
    const int nbase = b * NPB;
    const int nloc = (NPB < NN - nbase) ? NPB : NN - nbase;
    for (int i = tid; i < nloc; i += 256) hist[i] = deg[nbase + i];
    __syncthreads();
    for (int dl = tid; dl < nloc; dl += 256)
        dinv[nbase + dl] = rsqrtf((float)hist[dl] + 1.0f);
    __syncthreads();
    if (tid < 64) {                       // wave-0 exclusive scan of hist
        int carry = 0;
        for (int c0 = 0; c0 < NPB; c0 += 64) {
            int idx = c0 + tid;
            int orig = (idx < nloc) ? hist[idx] : 0;
            int v = orig;
#pragma unroll
            for (int off = 1; off < 64; off <<= 1) {
                int t = __shfl_up(v, off);
                if (tid >= off) v += t;
            }
            if (idx < NPB) hist[idx] = v - orig + carry;
            carry += __shfl(v, 63);
        }
    }
    __syncthreads();
    const int gbase = barr[b];
    for (int dl = tid; dl < nloc; dl += 256) {
        int rp = gbase + hist[dl];
        rowptr[nbase + dl] = rp;
        cursor[nbase + dl] = rp;
    }
}

// scatter edges: pos = cursor[dst]++, csr[pos] = src
__global__ __launch_bounds__(256) void k_fill(const int* __restrict__ src,
                                              const int* __restrict__ dst,
                                              int* __restrict__ cursor,
                                              int* __restrict__ csr) {
    int i = blockIdx.x * 256 + threadIdx.x;     // indexes int4
    if (i < NE / 4) {
        int4 s = ((const int4*)src)[i];
        int4 d = ((const int4*)dst)[i];
        int p0 = atomicAdd(&cursor[d.x], 1); csr[p0] = s.x;
        int p1 = atomicAdd(&cursor[d.y], 1); csr[p1] = s.y;
        int p2 = atomicAdd(&cursor[d.z], 1); csr[p2] = s.z;
        int p3 = atomicAdd(&cursor[d.w], 1); csr[p3] = s.w;
    }
}

// ---------------- weight -> f16 fragment-major conversion ----------------
__global__ __launch_bounds__(256) void k_wconv(
        const float* __restrict__ W0, const float* __restrict__ Wres,
        const float* __restrict__ W1, const float* __restrict__ W2,
        const float* __restrict__ Wl0, const float* __restrict__ Wl1,
        half8* __restrict__ F0, half8* __restrict__ Fres,
        half8* __restrict__ F1, half8* __restrict__ F2,
        half8* __restrict__ Fl0, half8* __restrict__ Fl1) {
    int f = blockIdx.x * 256 + threadIdx.x;
    const float* W; half8* F; int M, base;
    if      (f <  4096) { W = W0;   F = F0;   M = 128; base = 0; }
    else if (f <  8192) { W = Wres; F = Fres; M = 128; base = 4096; }
    else if (f < 10240) { W = W1;   F = F1;   M = 128; base = 8192; }
    else if (f < 12288) { W = W2;   F = F2;   M = 128; base = 10240; }
    else if (f < 14336) { W = Wl0;  F = Fl0;  M = 128; base = 12288; }
    else if (f < 15360) { W = Wl1;  F = Fl1;  M = 64;  base = 14336; }
    else return;
    int fl = f - base;
    int lane = fl & 63, fm = lane & 15, g = lane >> 4;
    int rest = fl >> 6;
    int nt = M / 16;
    int t = rest % nt, kt = rest / nt;
    half8 v;
#pragma unroll
    for (int j = 0; j < 8; ++j)
        v[j] = (_Float16)W[(size_t)(kt * 32 + g * 8 + j) * M + t * 16 + fm];
    F[fl] = v;
}

// ---------------- layer 0 GEMM: LDS-staged A AND B, 2-phase pipeline ---------
// C[N,256] = x[N,256] @ [W0|Wres]. 256 thr, 64 rows/block, K-step 32.
// Per step: issue next A+B global loads -> regs, compute from LDS, write staged
// regs to other buf, one barrier. (Verified R6: removed the per-MFMA global
// B-load latency chain; 139 -> <101 us.)
__global__ __launch_bounds__(256) void k_mfma0(const float* __restrict__ x,
                                               const half8* __restrict__ WF,
                                               const half8* __restrict__ WFb,
                                               const float* __restrict__ bres,
                                               const float* __restrict__ dinv,
                                               f16* __restrict__ lout,
                                               f16* __restrict__ rout) {
    constexpr int APAD = 40;
    __shared__ __align__(16) _Float16 Al[2][64 * APAD];   // 10.0 KB
    __shared__ __align__(16) _Float16 Bl[2][16 * 512];    // 32.0 KB
    const int tid = threadIdx.x;
    const int wave = tid >> 6, lane = tid & 63;
    const int fm = lane & 15, g = lane >> 4;
    const int rb = blockIdx.x * 64;

    // A staging: 4 threads/row, 8 consecutive floats each (fully coalesced)
    const int arow = tid >> 2;
    const int koff = (tid & 3) * 8;
    const int grow = rb + arow;
    const bool live = (grow < NN);
    const float* xp = x + (size_t)(live ? grow : 0) * CIN + koff;

    // B staging: wave w stages frags 4w..4w+3 (1KB each, coalesced per wave)
    const int bt = wave * 4;

    floatx4 acc[16];
#pragma unroll
    for (int t = 0; t < 16; ++t)
#pragma unroll
        for (int r = 0; r < 4; ++r) acc[t][r] = 0.0f;

    float4 a0, a1;           // A-chunk in flight
    half8 rB[4];             // B-frags in flight

    auto ldA = [&](int kt) {
        if (live) {
            a0 = *(const float4*)(xp + kt * 32);
            a1 = *(const float4*)(xp + kt * 32 + 4);
        } else {
            a0 = make_float4(0.f, 0.f, 0.f, 0.f);
            a1 = make_float4(0.f, 0.f, 0.f, 0.f);
        }
    };
    auto ldB = [&](int kt) {
#pragma unroll
        for (int i = 0; i < 4; ++i) {
            int t = bt + i;
            rB[i] = (t < 8) ? WF[((size_t)kt * 8 + t) * 64 + lane]
                            : WFb[((size_t)kt * 8 + (t - 8)) * 64 + lane];
        }
    };
    auto stA = [&](int buf) {
        half8 h;
        h[0] = (_Float16)a0.x; h[1] = (_Float16)a0.y;
        h[2] = (_Float16)a0.z; h[3] = (_Float16)a0.w;
        h[4] = (_Float16)a1.x; h[5] = (_Float16)a1.y;
        h[6] = (_Float16)a1.z; h[7] = (_Float16)a1.w;
        *(half8*)&Al[buf][arow * APAD + koff] = h;
    };
    auto stB = [&](int buf) {
#pragma unroll
        for (int i = 0; i < 4; ++i)
            *(half8*)&Bl[buf][(bt + i) * 512 + lane * 8] = rB[i];
    };

    // prologue: stage step 0 into buf 0
    ldA(0); ldB(0);
    stA(0); stB(0);
    __syncthreads();

    for (int kt = 0; kt < 8; ++kt) {
        const int cur = kt & 1;
        if (kt < 7) { ldA(kt + 1); ldB(kt + 1); }    // issue-early: hides under compute
        half8 afrag = *(const half8*)&Al[cur][(wave * 16 + fm) * APAD + g * 8];
#pragma unroll
        for (int t = 0; t < 8; ++t) {
            half8 bfrag = *(const half8*)&Bl[cur][t * 512 + lane * 8];
            acc[t] = __builtin_amdgcn_mfma_f32_16x16x32_f16(afrag, bfrag, acc[t], 0, 0, 0);
        }
#pragma unroll
        for (int t = 0; t < 8; ++t) {
            half8 bfrag = *(const half8*)&Bl[cur][(8 + t) * 512 + lane * 8];
            acc[8 + t] = __builtin_amdgcn_mfma_f32_16x16x32_f16(afrag, bfrag, acc[8 + t], 0, 0, 0);
        }
        if (kt < 7) { stA(cur ^ 1); stB(cur ^ 1); }  // write-late, after compute
        __syncthreads();
    }

    const int rloc = wave * 16 + g * 4;
#pragma unroll
    for (int t = 0; t < 8; ++t) {
        int col = t * 16 + fm;
#pragma unroll
        for (int r = 0; r < 4; ++r) {
            int row = rb + rloc + r;
            if (row < NN) lout[(size_t)row * 128 + col] = (f16)(acc[t][r] * dinv[row]);
        }
    }
#pragma unroll
    for (int t = 0; t < 8; ++t) {
        int col = t * 16 + fm;
        float bb = bres[col];
#pragma unroll
        for (int r = 0; r < 4; ++r) {
            int row = rb + rloc + r;
            if (row < NN) rout[(size_t)row * 128 + col] = (f16)(acc[8 + t][r] + bb);
        }
    }
}

// ---------------- f16 GEMM, barrier-free: layers 1 & 2 ----------------
__global__ __launch_bounds__(256) void k_lin(const f16* __restrict__ A,
                                             const half8* __restrict__ WF,
                                             const float* __restrict__ dinv,
                                             f16* __restrict__ lout) {
    const int tid = threadIdx.x;
    const int wave = tid >> 6, lane = tid & 63;
    const int fm = lane & 15, g = lane >> 4;
    const int tb = blockIdx.x * 64 + wave * 16;   // this wave's 16-row tile
    const int arow = tb + fm;

    half8 af[4];
#pragma unroll
    for (int kt = 0; kt < 4; ++kt) {
        if (arow < NN) {
            af[kt] = *(const half8*)((const _Float16*)A + (size_t)arow * CH + kt * 32 + g * 8);
        } else {
#pragma unroll
            for (int i = 0; i < 8; ++i) af[kt][i] = (_Float16)0.0f;
        }
    }

    floatx4 acc[8];
#pragma unroll
    for (int t = 0; t < 8; ++t)
#pragma unroll
        for (int r = 0; r < 4; ++r) acc[t][r] = 0.0f;

#pragma unroll
    for (int kt = 0; kt < 4; ++kt)
#pragma unroll
        for (int t = 0; t < 8; ++t)
            acc[t] = __builtin_amdgcn_mfma_f32_16x16x32_f16(
                af[kt], WF[((size_t)kt * 8 + t) * 64 + lane], acc[t], 0, 0, 0);

#pragma unroll
    for (int t = 0; t < 8; ++t) {
        int col = t * 16 + fm;
#pragma unroll
        for (int r = 0; r < 4; ++r) {
            int row = tb + g * 4 + r;
            if (row < NN) lout[(size_t)row * CH + col] = (f16)(acc[t][r] * dinv[row]);
        }
    }
}

// ---------------- fused head MLP: relu(h@Wl0+bl0)@Wl1+bl1 ----------------
__global__ __launch_bounds__(256) void k_head(const f16* __restrict__ A,
                                              const half8* __restrict__ WF0,
                                              const half8* __restrict__ WF1,
                                              const float* __restrict__ bl0,
                                              const float* __restrict__ bl1,
                                              float* __restrict__ outp) {
    constexpr int LP = 136;                        // LDS pitch (halves), 272B rows
    __shared__ __align__(16) _Float16 Hs[64 * LP];
    const int tid = threadIdx.x;
    const int wave = tid >> 6, lane = tid & 63;
    const int fm = lane & 15, g = lane >> 4;
    const int tb = blockIdx.x * 64 + wave * 16;
    const int arow = tb + fm;

    half8 af[4];
#pragma unroll
    for (int kt = 0; kt < 4; ++kt) {
        if (arow < NN) {
            af[kt] = *(const half8*)((const _Float16*)A + (size_t)arow * CH + kt * 32 + g * 8);
        } else {
#pragma unroll
            for (int i = 0; i < 8; ++i) af[kt][i] = (_Float16)0.0f;
        }
    }

    floatx4 acc[8];
#pragma unroll
    for (int t = 0; t < 8; ++t)
#pragma unroll
        for (int r = 0; r < 4; ++r) acc[t][r] = 0.0f;

#pragma unroll
    for (int kt = 0; kt < 4; ++kt)
#pragma unroll
        for (int t = 0; t < 8; ++t)
            acc[t] = __builtin_amdgcn_mfma_f32_16x16x32_f16(
                af[kt], WF0[((size_t)kt * 8 + t) * 64 + lane], acc[t], 0, 0, 0);

    // epilogue 1: bias + ReLU -> LDS (always write: keeps LDS finite for tail rows)
    const int lrow = wave * 16 + g * 4;
#pragma unroll
    for (int t = 0; t < 8; ++t) {
        int col = t * 16 + fm;
        float b = bl0[col];
#pragma unroll
        for (int r = 0; r < 4; ++r)
            Hs[(lrow + r) * LP + col] = (_Float16)fmaxf(acc[t][r] + b, 0.0f);
    }
    __syncthreads();

    // GEMM2: M=64, A from LDS
    floatx4 acc2[4];
#pragma unroll
    for (int t = 0; t < 4; ++t)
#pragma unroll
        for (int r = 0; r < 4; ++r) acc2[t][r] = 0.0f;

#pragma unroll
    for (int kt = 0; kt < 4; ++kt) {
        half8 a2 = *(const half8*)&Hs[(wave * 16 + fm) * LP + kt * 32 + g * 8];
#pragma unroll
        for (int t = 0; t < 4; ++t)
            acc2[t] = __builtin_amdgcn_mfma_f32_16x16x32_f16(
                a2, WF1[((size_t)kt * 4 + t) * 64 + lane], acc2[t], 0, 0, 0);
    }

#pragma unroll
    for (int t = 0; t < 4; ++t) {
        int col = t * 16 + fm;
        float b = bl1[col];
#pragma unroll
        for (int r = 0; r < 4; ++r) {
            int row = tb + g * 4 + r;
            if (row < NN) outp[(size_t)row * COUT + col] = acc2[t][r] + b;
        }
    }
}

// ---------------- CSR gather + BN + ReLU (+residual) ----------------
template <bool RES>
__global__ __launch_bounds__(256) void k_gather(const int* __restrict__ rowptr,
                                                const int* __restrict__ csr,
                                                const float* __restrict__ dinv,
                                                const f16* __restrict__ lin,
                                                const f16* __restrict__ res,
                                                f16* __restrict__ h,
                                                const float* __restrict__ b,
                                                const float* __restrict__ g,
                                                const float* __restrict__ be) {
    const int gw = (blockIdx.x * 256 + threadIdx.x) >> 6;
    const int lane = threadIdx.x & 63;
    if (gw >= NN) return;
    const __half2* lp = (const __half2*)lin;
    // wave-uniform bounds -> scalar loop + uniform csr index stream
    const int start = __builtin_amdgcn_readfirstlane(rowptr[gw]);
    const int end   = __builtin_amdgcn_readfirstlane(rowptr[gw + 1]);

    float2 acc = __half22float2(lp[(size_t)gw * 64 + lane]);  // self term
    int j = start;
    for (; j + 7 < end; j += 8) {
        int s0 = csr[j],     s1 = csr[j + 1], s2 = csr[j + 2], s3 = csr[j + 3];
        int s4 = csr[j + 4], s5 = csr[j + 5], s6 = csr[j + 6], s7 = csr[j + 7];
        float2 v0 = __half22float2(lp[(size_t)s0 * 64 + lane]);
        float2 v1 = __half22float2(lp[(size_t)s1 * 64 + lane]);
        float2 v2 = __half22float2(lp[(size_t)s2 * 64 + lane]);
        float2 v3 = __half22float2(lp[(size_t)s3 * 64 + lane]);
        float2 v4 = __half22float2(lp[(size_t)s4 * 64 + lane]);
        float2 v5 = __half22float2(lp[(size_t)s5 * 64 + lane]);
        float2 v6 = __half22float2(lp[(size_t)s6 * 64 + lane]);
        float2 v7 = __half22float2(lp[(size_t)s7 * 64 + lane]);
        acc.x += ((v0.x + v1.x) + (v2.x + v3.x)) + ((v4.x + v5.x) + (v6.x + v7.x));
        acc.y += ((v0.y + v1.y) + (v2.y + v3.y)) + ((v4.y + v5.y) + (v6.y + v7.y));
    }
    for (; j + 3 < end; j += 4) {
        int s0 = csr[j], s1 = csr[j + 1], s2 = csr[j + 2], s3 = csr[j + 3];
        float2 v0 = __half22float2(lp[(size_t)s0 * 64 + lane]);
        float2 v1 = __half22float2(lp[(size_t)s1 * 64 + lane]);
        float2 v2 = __half22float2(lp[(size_t)s2 * 64 + lane]);
        float2 v3 = __half22float2(lp[(size_t)s3 * 64 + lane]);
        acc.x += (v0.x + v1.x) + (v2.x + v3.x);
        acc.y += (v0.y + v1.y) + (v2.y + v3.y);
    }
    for (; j < end; ++j) {
        int s = csr[j];
        float2 v = __half22float2(lp[(size_t)s * 64 + lane]);
        acc.x += v.x;
        acc.y += v.y;
    }
    const float inv_sqrt = 0.99999500003749968f;  // 1/sqrt(1+1e-5)
    float dv = dinv[gw];
    int f = lane * 2;
    float2 bb = *(const float2*)&b[f];
    float2 gg = *(const float2*)&g[f];
    float2 ee = *(const float2*)&be[f];
    float t0 = fmaxf((acc.x * dv + bb.x) * (gg.x * inv_sqrt) + ee.x, 0.0f);
    float t1 = fmaxf((acc.y * dv + bb.y) * (gg.y * inv_sqrt) + ee.y, 0.0f);
    if (RES) {
        float2 rv = __half22float2(((const __half2*)res)[(size_t)gw * 64 + lane]);
        t0 += rv.x;
        t1 += rv.y;
    }
    ((__half2*)h)[(size_t)gw * 64 + lane] = __floats2half2_rn(t0, t1);
}

// ---------------- pooling ----------------
__global__ void k_count(const int* __restrict__ batch, float* __restrict__ cnt) {
    __shared__ float hist[NB];
    int tid = threadIdx.x;
    if (tid < NB) hist[tid] = 0.0f;
    __syncthreads();
    int n = blockIdx.x * 256 + tid;
    if (n < NN) atomicAdd(&hist[batch[n]], 1.0f);
    __syncthreads();
    if (tid < NB && hist[tid] != 0.0f) atomicAdd(&cnt[tid], hist[tid]);
}

__global__ void k_pool(const f16* __restrict__ h, const int* __restrict__ batch,
                       float* __restrict__ pool) {
    int n0 = blockIdx.x * 64;
    int j = threadIdx.x;
    int cur = batch[n0];
    float acc = 0.0f;
    int nend = (n0 + 64 < NN) ? n0 + 64 : NN;
    for (int n = n0; n < nend; ++n) {
        int b = batch[n];
        if (b != cur) {
            atomicAdd(&pool[cur * CH + j], acc);
            acc = 0.0f;
            cur = b;
        }
        acc += (float)h[(size_t)n * CH + j];
    }
    atomicAdd(&pool[cur * CH + j], acc);
}

__global__ void k_pool_fin(const float* __restrict__ pool,
                           const float* __restrict__ cnt,
                           float* __restrict__ out) {
    int i = blockIdx.x * 256 + threadIdx.x;
    if (i < NB * CH) {
        float c = fmaxf(cnt[i / CH], 1.0f);
        out[i] = pool[i] / c;
    }
}

// ---------------- launch ----------------
extern "C" void kernel_launch(void* const* d_in, const int* in_sizes, int n_in,
                              void* d_out, int out_size, void* d_ws, size_t ws_size,
                              hipStream_t stream) {
    float* outp  = (float*)d_out;                  // [NN, COUT] f32
    float* poolp = outp + (size_t)NN * COUT;       // [NB, CH] f32

    // ---- workspace layout (deg/cursor alias rbuf: used only pre-layer0) ----
    const size_t HB = (size_t)NN * CH * 2;         // f16 h          25.6 MB
    const size_t LB = (size_t)NN * CH * 2;         // f16 linscaled  25.6 MB
    const size_t RB = (size_t)NN * CH * 2;         // f16 residual / deg+cursor alias
    const size_t DV = (size_t)NN * 4;
    const size_t RP = 400016;                      // (NN+1)*4 padded to 16
    const size_t CS = (size_t)NE * 4;
    const size_t GC = 512;                         // bsum 128 ints
    const size_t BA = 528;                         // barr 128+pad
    const size_t PL = (size_t)NB * CH * 4;
    const size_t CT = 256;
    const size_t F0B = 4096 * 16, F1B = 2048 * 16, FLB = 1024 * 16;
    const size_t need = HB + LB + RB + DV + RP + CS + GC + BA + PL + CT
                        + 2 * F0B + 3 * F1B + FLB;
    if (ws_size < need) {
        k_sentinel<<<(out_size + 255) / 256, 256, 0, stream>>>(outp, out_size, 2000.0f);
        return;
    }
    char* p = (char*)d_ws;
    f16*   hbuf   = (f16*)p;               p += HB;
    f16*   lbuf   = (f16*)p;               p += LB;
    f16*   rbuf   = (f16*)p;
    int*   deg    = (int*)p;                         // alias (pre-layer0 only)
    int*   cursor = (int*)p + 100096;                // alias (pre-layer0 only)
    p += RB;
    float* dinv   = (float*)p;             p += DV;
    int*   rowptr = (int*)p;               p += RP;
    int*   csr    = (int*)p;               p += CS;
    int*   bsum   = (int*)p;               p += GC;
    int*   barr   = (int*)p;               p += BA;
    float* pool   = (float*)p;             p += PL;
    float* cnt    = (float*)p;             p += CT;
    half8* F0     = (half8*)p;             p += F0B;
    half8* Fres   = (half8*)p;             p += F0B;
    half8* F1     = (half8*)p;             p += F1B;
    half8* F2     = (half8*)p;             p += F1B;
    half8* Fl0    = (half8*)p;             p += F1B;
    half8* Fl1    = (half8*)p;

    const float* x   = (const float*)d_in[0];
    const int*   ei  = (const int*)d_in[1];
    const int*   bat = (const int*)d_in[2];
    const float* W0 = (const float*)d_in[3],  *b0 = (const float*)d_in[4];
    const float* W1 = (const float*)d_in[5],  *b1 = (const float*)d_in[6];
    const float* W2 = (const float*)d_in[7],  *b2 = (const float*)d_in[8];
    const float* g0 = (const float*)d_in[9],  *be0 = (const float*)d_in[10];
    const float* g1 = (const float*)d_in[11], *be1 = (const float*)d_in[12];
    const float* g2 = (const float*)d_in[13], *be2 = (const float*)d_in[14];
    const float* Wres = (const float*)d_in[15], *bres = (const float*)d_in[16];
    const float* Wl0 = (const float*)d_in[17], *bl0 = (const float*)d_in[18];
    const float* Wl1 = (const float*)d_in[19], *bl1 = (const float*)d_in[20];

    const int* src = ei;
    const int* dst = ei + NE;

    const int gRow = (NN + 63) / 64;              // 1563
    const int gGat = (NN * 64) / 256;             // 25000
    const int gE4  = (NE / 4 + 255) / 256;        // 1563

    // ---- CSR build: counting sort (deg -> scan -> fill) ----
    k_init<<<(NN + 255) / 256, 256, 0, stream>>>(pool, cnt, deg);
    k_wconv<<<60, 256, 0, stream>>>(W0, Wres, W1, W2, Wl0, Wl1,
                                    F0, Fres, F1, F2, Fl0, Fl1);
    k_deg<<<gE4, 256, 0, stream>>>(dst, deg);
    k_bsum<<<NBUK, 256, 0, stream>>>(deg, bsum);
    k_scanb<<<1, 64, 0, stream>>>(bsum, barr, rowptr);
    k_brow<<<NBUK, 256, 0, stream>>>(deg, barr, rowptr, cursor, dinv);
    k_fill<<<gE4, 256, 0, stream>>>(src, dst, cursor, csr);

    // ---- layer 0 fused with residual: LDS-staged A+B, 2-phase pipeline ----
    k_mfma0<<<gRow, 256, 0, stream>>>(x, F0, Fres, bres, dinv, lbuf, rbuf);
    k_gather<true><<<gGat, 256, 0, stream>>>(rowptr, csr, dinv, lbuf, rbuf, hbuf, b0, g0, be0);

    // ---- layer 1 (barrier-free f16 GEMM) ----
    k_lin<<<gRow, 256, 0, stream>>>(hbuf, F1, dinv, lbuf);
    k_gather<false><<<gGat, 256, 0, stream>>>(rowptr, csr, dinv, lbuf, nullptr, hbuf, b1, g1, be1);

    // ---- layer 2 ----
    k_lin<<<gRow, 256, 0, stream>>>(hbuf, F2, dinv, lbuf);
    k_gather<false><<<gGat, 256, 0, stream>>>(rowptr, csr, dinv, lbuf, nullptr, hbuf, b2, g2, be2);

    // ---- mean pool over graphs (final h) ----
    k_count<<<(NN + 255) / 256, 256, 0, stream>>>(bat, cnt);
    k_pool<<<gRow, 128, 0, stream>>>(hbuf, bat, pool);
    k_pool_fin<<<(NB * CH + 255) / 256, 256, 0, stream>>>(pool, cnt, poolp);

    // ---- fused head MLP ----
    k_head<<<gRow, 256, 0, stream>>>(hbuf, Fl0, Fl1, bl0, bl1, outp);
}

// Round 11
// 588.523 us; speedup vs baseline: 1.2294x; 1.2294x over previous
//
#include <hip/hip_runtime.h>
#include <hip/hip_fp16.h>

typedef __half f16;
typedef _Float16 half8 __attribute__((ext_vector_type(8)));
typedef float floatx4 __attribute__((ext_vector_type(4)));

#define NN   100000   // nodes
#define NE   1600000  // edges
#define CIN  256
#define CH   128
#define COUT 64
#define NB   64

#define NBUK 128      // CSR buckets
#define NPB  782      // nodes per bucket (128*782 = 100096 >= NN)
#define BCAP 32       // LDS bin slots per bucket (k_bin); in-round mean 8
#define CAPB 20480    // staging capacity per bucket (mean 12500)
#define G1   400      // k_bin blocks
#define EPB  4000     // edges per k_bin block (400*4000 = NE, int4-aligned)
#define CSZ  15104    // k_csr LDS csr entries (60.4KB; mean 12500, +23 sigma)

// ---------------- diagnostics ----------------
__global__ void k_sentinel(float* __restrict__ out, int n, float val) {
    int i = blockIdx.x * 256 + threadIdx.x;
    if (i < n) out[i] = val;
}

// ---------------- init: pool/cnt zero, bucket cursors ----------------
__global__ void k_init(float* __restrict__ pool, float* __restrict__ cnt,
                       int* __restrict__ gcur) {
    int i = blockIdx.x * 256 + threadIdx.x;
    if (i < NB * CH) pool[i] = 0.0f;
    if (i < NB) cnt[i] = 0.0f;
    if (i < NBUK) gcur[i] = i * CAPB;
}

// ---------------- phase 1: bin edges by dst bucket ----------------
// stage[gcur[b]++] = (dst%NPB)<<17 | src. int4 loads: 1024 edges/round,
// 4 rounds/block, 3 barriers/round, flush-all (no compact). [R8: k_fill's
// raw 4B scatter write-amplified 17x at HBM -- LDS binning + chunked flush
// is load-bearing.]
__global__ __launch_bounds__(256) void k_bin(const int* __restrict__ src,
                                             const int* __restrict__ dst,
                                             int* __restrict__ gcur,
                                             int* __restrict__ stage) {
    __shared__ int bins[NBUK][BCAP];
    __shared__ int bcnt[NBUK];
    __shared__ int fcnt[NBUK];
    __shared__ int fbase[NBUK];
    const int tid = threadIdx.x;
    if (tid < NBUK) bcnt[tid] = 0;
    __syncthreads();
    const int i0 = blockIdx.x * (EPB / 4);          // int4 index base
    const int i1 = (i0 + EPB / 4 < NE / 4) ? i0 + EPB / 4 : NE / 4;
    for (int base = i0; base < i1; base += 256) {
        int idx = base + tid;
        if (idx < i1) {
            int4 s4 = ((const int4*)src)[idx];
            int4 d4 = ((const int4*)dst)[idx];
            int ss[4] = {s4.x, s4.y, s4.z, s4.w};
            int dd[4] = {d4.x, d4.y, d4.z, d4.w};
#pragma unroll
            for (int e = 0; e < 4; ++e) {
                int d = dd[e];
                int bk = d / NPB;                   // magic-mul (const)
                int pk = ((d - bk * NPB) << 17) | ss[e];
                int pos = atomicAdd(&bcnt[bk], 1);
                if (pos < BCAP) {
                    bins[bk][pos] = pk;
                } else {                             // rare in-round overflow
                    int gp = atomicAdd(&gcur[bk], 1);
                    if (gp < (bk + 1) * CAPB) stage[gp] = pk;
                }
            }
        }
        __syncthreads();
        if (tid < NBUK) {                            // plan flush (all stored)
            int stored = bcnt[tid]; if (stored > BCAP) stored = BCAP;
            fcnt[tid] = stored;
            fbase[tid] = stored ? atomicAdd(&gcur[tid], stored) : 0;
            bcnt[tid] = 0;
        }
        __syncthreads();
#pragma unroll
        for (int pass = 0; pass < NBUK / 16; ++pass) {   // coalesced flush
            int b = pass * 16 + (tid >> 4);
            int sl = tid & 15;
            int nf = fcnt[b];
            int fb = fbase[b];
            for (int k = sl; k < nf; k += 16)
                if (fb + k < (b + 1) * CAPB) stage[fb + k] = bins[b][k];
        }
        __syncthreads();
    }
}

// ---------------- phase 1b: scan bucket totals -> csr bases ----------------
__global__ void k_gtot(const int* __restrict__ gcur, int* __restrict__ barr,
                       int* __restrict__ rowptr) {
    int lane = threadIdx.x;   // 64 threads
    int carry = 0;
    for (int c0 = 0; c0 < NBUK; c0 += 64) {
        int idx = c0 + lane;
        int orig = gcur[idx] - idx * CAPB;
        int v = orig;
#pragma unroll
        for (int off = 1; off < 64; off <<= 1) {
            int t = __shfl_up(v, off);
            if (lane >= off) v += t;
        }
        barr[idx] = v - orig + carry;
        carry += __shfl(v, 63);
    }
    if (lane == 0) rowptr[NN] = NE;
}

// ---------------- phase 2: per-bucket CSR + rowptr + dinv ----------------
__global__ __launch_bounds__(256) void k_csr(const int* __restrict__ gcur,
                                             const int* __restrict__ barr,
                                             const int* __restrict__ stage,
                                             int* __restrict__ rowptr,
                                             int* __restrict__ csr,
                                             float* __restrict__ dinv) {
    __shared__ int hist[NPB];
    __shared__ int lcsr[CSZ];
    const int b = blockIdx.x, tid = threadIdx.x;
    const int nbase = b * NPB;
    const int nloc = (NPB < NN - nbase) ? NPB : NN - nbase;
    const int count = gcur[b] - b * CAPB;
    const int gbase = barr[b];
    const int sb = b * CAPB;
    for (int i = tid; i < NPB; i += 256) hist[i] = 0;
    __syncthreads();
    for (int i = tid; i < count; i += 256)
        atomicAdd(&hist[stage[sb + i] >> 17], 1);
    __syncthreads();
    for (int dl = tid; dl < nloc; dl += 256)
        dinv[nbase + dl] = rsqrtf((float)hist[dl] + 1.0f);
    __syncthreads();
    if (tid < 64) {                       // wave-0 exclusive scan of hist
        int carry = 0;
        for (int c0 = 0; c0 < NPB; c0 += 64) {
            int idx = c0 + tid;
            int orig = (idx < NPB) ? hist[idx] : 0;
            int v = orig;
#pragma unroll
            for (int off = 1; off < 64; off <<= 1) {
                int t = __shfl_up(v, off);
                if (tid >= off) v += t;
            }
            if (idx < NPB) hist[idx] = v - orig + carry;
            carry += __shfl(v, 63);
        }
    }
    __syncthreads();
    for (int dl = tid; dl < nloc; dl += 256)
        rowptr[nbase + dl] = gbase + hist[dl];
    __syncthreads();
    const bool fits = (count <= CSZ);
    for (int i = tid; i < count; i += 256) {
        int pk = stage[sb + i];
        int dl = pk >> 17, s = pk & 0x1FFFF;
        int pos = atomicAdd(&hist[dl], 1);
        if (fits) lcsr[pos] = s;
        else csr[gbase + pos] = s;        // fallback (pathological skew only)
    }
    __syncthreads();
    if (fits)
        for (int i = tid; i < count; i += 256) csr[gbase + i] = lcsr[i];
}

// ---------------- weight -> f16 fragment-major conversion ----------------
__global__ __launch_bounds__(256) void k_wconv(
        const float* __restrict__ W0, const float* __restrict__ Wres,
        const float* __restrict__ W1, const float* __restrict__ W2,
        const float* __restrict__ Wl0, const float* __restrict__ Wl1,
        half8* __restrict__ F0, half8* __restrict__ Fres,
        half8* __restrict__ F1, half8* __restrict__ F2,
        half8* __restrict__ Fl0, half8* __restrict__ Fl1) {
    int f = blockIdx.x * 256 + threadIdx.x;
    const float* W; half8* F; int M, base;
    if      (f <  4096) { W = W0;   F = F0;   M = 128; base = 0; }
    else if (f <  8192) { W = Wres; F = Fres; M = 128; base = 4096; }
    else if (f < 10240) { W = W1;   F = F1;   M = 128; base = 8192; }
    else if (f < 12288) { W = W2;   F = F2;   M = 128; base = 10240; }
    else if (f < 14336) { W = Wl0;  F = Fl0;  M = 128; base = 12288; }
    else if (f < 15360) { W = Wl1;  F = Fl1;  M = 64;  base = 14336; }
    else return;
    int fl = f - base;
    int lane = fl & 63, fm = lane & 15, g = lane >> 4;
    int rest = fl >> 6;
    int nt = M / 16;
    int t = rest % nt, kt = rest / nt;
    half8 v;
#pragma unroll
    for (int j = 0; j < 8; ++j)
        v[j] = (_Float16)W[(size_t)(kt * 32 + g * 8 + j) * M + t * 16 + fm];
    F[fl] = v;
}

// ---------------- layer 0 GEMM: LDS-staged A AND B, 2-phase pipeline ---------
// (Verified R6: B in LDS removed the per-MFMA global-load latency chain.)
__global__ __launch_bounds__(256) void k_mfma0(const float* __restrict__ x,
                                               const half8* __restrict__ WF,
                                               const half8* __restrict__ WFb,
                                               const float* __restrict__ bres,
                                               const float* __restrict__ dinv,
                                               f16* __restrict__ lout,
                                               f16* __restrict__ rout) {
    constexpr int APAD = 40;
    __shared__ __align__(16) _Float16 Al[2][64 * APAD];   // 10.0 KB
    __shared__ __align__(16) _Float16 Bl[2][16 * 512];    // 32.0 KB
    const int tid = threadIdx.x;
    const int wave = tid >> 6, lane = tid & 63;
    const int fm = lane & 15, g = lane >> 4;
    const int rb = blockIdx.x * 64;

    const int arow = tid >> 2;
    const int koff = (tid & 3) * 8;
    const int grow = rb + arow;
    const bool live = (grow < NN);
    const float* xp = x + (size_t)(live ? grow : 0) * CIN + koff;

    const int bt = wave * 4;

    floatx4 acc[16];
#pragma unroll
    for (int t = 0; t < 16; ++t)
#pragma unroll
        for (int r = 0; r < 4; ++r) acc[t][r] = 0.0f;

    float4 a0, a1;
    half8 rB[4];

    auto ldA = [&](int kt) {
        if (live) {
            a0 = *(const float4*)(xp + kt * 32);
            a1 = *(const float4*)(xp + kt * 32 + 4);
        } else {
            a0 = make_float4(0.f, 0.f, 0.f, 0.f);
            a1 = make_float4(0.f, 0.f, 0.f, 0.f);
        }
    };
    auto ldB = [&](int kt) {
#pragma unroll
        for (int i = 0; i < 4; ++i) {
            int t = bt + i;
            rB[i] = (t < 8) ? WF[((size_t)kt * 8 + t) * 64 + lane]
                            : WFb[((size_t)kt * 8 + (t - 8)) * 64 + lane];
        }
    };
    auto stA = [&](int buf) {
        half8 h;
        h[0] = (_Float16)a0.x; h[1] = (_Float16)a0.y;
        h[2] = (_Float16)a0.z; h[3] = (_Float16)a0.w;
        h[4] = (_Float16)a1.x; h[5] = (_Float16)a1.y;
        h[6] = (_Float16)a1.z; h[7] = (_Float16)a1.w;
        *(half8*)&Al[buf][arow * APAD + koff] = h;
    };
    auto stB = [&](int buf) {
#pragma unroll
        for (int i = 0; i < 4; ++i)
            *(half8*)&Bl[buf][(bt + i) * 512 + lane * 8] = rB[i];
    };

    ldA(0); ldB(0);
    stA(0); stB(0);
    __syncthreads();

    for (int kt = 0; kt < 8; ++kt) {
        const int cur = kt & 1;
        if (kt < 7) { ldA(kt + 1); ldB(kt + 1); }
        half8 afrag = *(const half8*)&Al[cur][(wave * 16 + fm) * APAD + g * 8];
#pragma unroll
        for (int t = 0; t < 8; ++t) {
            half8 bfrag = *(const half8*)&Bl[cur][t * 512 + lane * 8];
            acc[t] = __builtin_amdgcn_mfma_f32_16x16x32_f16(afrag, bfrag, acc[t], 0, 0, 0);
        }
#pragma unroll
        for (int t = 0; t < 8; ++t) {
            half8 bfrag = *(const half8*)&Bl[cur][(8 + t) * 512 + lane * 8];
            acc[8 + t] = __builtin_amdgcn_mfma_f32_16x16x32_f16(afrag, bfrag, acc[8 + t], 0, 0, 0);
        }
        if (kt < 7) { stA(cur ^ 1); stB(cur ^ 1); }
        __syncthreads();
    }

    const int rloc = wave * 16 + g * 4;
#pragma unroll
    for (int t = 0; t < 8; ++t) {
        int col = t * 16 + fm;
#pragma unroll
        for (int r = 0; r < 4; ++r) {
            int row = rb + rloc + r;
            if (row < NN) lout[(size_t)row * 128 + col] = (f16)(acc[t][r] * dinv[row]);
        }
    }
#pragma unroll
    for (int t = 0; t < 8; ++t) {
        int col = t * 16 + fm;
        float bb = bres[col];
#pragma unroll
        for (int r = 0; r < 4; ++r) {
            int row = rb + rloc + r;
            if (row < NN) rout[(size_t)row * 128 + col] = (f16)(acc[8 + t][r] + bb);
        }
    }
}

// ---------------- f16 GEMM, barrier-free: layers 1 & 2 ----------------
__global__ __launch_bounds__(256) void k_lin(const f16* __restrict__ A,
                                             const half8* __restrict__ WF,
                                             const float* __restrict__ dinv,
                                             f16* __restrict__ lout) {
    const int tid = threadIdx.x;
    const int wave = tid >> 6, lane = tid & 63;
    const int fm = lane & 15, g = lane >> 4;
    const int tb = blockIdx.x * 64 + wave * 16;   // this wave's 16-row tile
    const int arow = tb + fm;

    half8 af[4];
#pragma unroll
    for (int kt = 0; kt < 4; ++kt) {
        if (arow < NN) {
            af[kt] = *(const half8*)((const _Float16*)A + (size_t)arow * CH + kt * 32 + g * 8);
        } else {
#pragma unroll
            for (int i = 0; i < 8; ++i) af[kt][i] = (_Float16)0.0f;
        }
    }

    floatx4 acc[8];
#pragma unroll
    for (int t = 0; t < 8; ++t)
#pragma unroll
        for (int r = 0; r < 4; ++r) acc[t][r] = 0.0f;

#pragma unroll
    for (int kt = 0; kt < 4; ++kt)
#pragma unroll
        for (int t = 0; t < 8; ++t)
            acc[t] = __builtin_amdgcn_mfma_f32_16x16x32_f16(
                af[kt], WF[((size_t)kt * 8 + t) * 64 + lane], acc[t], 0, 0, 0);

#pragma unroll
    for (int t = 0; t < 8; ++t) {
        int col = t * 16 + fm;
#pragma unroll
        for (int r = 0; r < 4; ++r) {
            int row = tb + g * 4 + r;
            if (row < NN) lout[(size_t)row * CH + col] = (f16)(acc[t][r] * dinv[row]);
        }
    }
}

// ---------------- fused head MLP: relu(h@Wl0+bl0)@Wl1+bl1 ----------------
__global__ __launch_bounds__(256) void k_head(const f16* __restrict__ A,
                                              const half8* __restrict__ WF0,
                                              const half8* __restrict__ WF1,
                                              const float* __restrict__ bl0,
                                              const float* __restrict__ bl1,
                                              float* __restrict__ outp) {
    constexpr int LP = 136;                        // LDS pitch (halves), 272B rows
    __shared__ __align__(16) _Float16 Hs[64 * LP];
    const int tid = threadIdx.x;
    const int wave = tid >> 6, lane = tid & 63;
    const int fm = lane & 15, g = lane >> 4;
    const int tb = blockIdx.x * 64 + wave * 16;
    const int arow = tb + fm;

    half8 af[4];
#pragma unroll
    for (int kt = 0; kt < 4; ++kt) {
        if (arow < NN) {
            af[kt] = *(const half8*)((const _Float16*)A + (size_t)arow * CH + kt * 32 + g * 8);
        } else {
#pragma unroll
            for (int i = 0; i < 8; ++i) af[kt][i] = (_Float16)0.0f;
        }
    }

    floatx4 acc[8];
#pragma unroll
    for (int t = 0; t < 8; ++t)
#pragma unroll
        for (int r = 0; r < 4; ++r) acc[t][r] = 0.0f;

#pragma unroll
    for (int kt = 0; kt < 4; ++kt)
#pragma unroll
        for (int t = 0; t < 8; ++t)
            acc[t] = __builtin_amdgcn_mfma_f32_16x16x32_f16(
                af[kt], WF0[((size_t)kt * 8 + t) * 64 + lane], acc[t], 0, 0, 0);

    // epilogue 1: bias + ReLU -> LDS (always write: keeps LDS finite for tail rows)
    const int lrow = wave * 16 + g * 4;
#pragma unroll
    for (int t = 0; t < 8; ++t) {
        int col = t * 16 + fm;
        float b = bl0[col];
#pragma unroll
        for (int r = 0; r < 4; ++r)
            Hs[(lrow + r) * LP + col] = (_Float16)fmaxf(acc[t][r] + b, 0.0f);
    }
    __syncthreads();

    // GEMM2: M=64, A from LDS
    floatx4 acc2[4];
#pragma unroll
    for (int t = 0; t < 4; ++t)
#pragma unroll
        for (int r = 0; r < 4; ++r) acc2[t][r] = 0.0f;

#pragma unroll
    for (int kt = 0; kt < 4; ++kt) {
        half8 a2 = *(const half8*)&Hs[(wave * 16 + fm) * LP + kt * 32 + g * 8];
#pragma unroll
        for (int t = 0; t < 4; ++t)
            acc2[t] = __builtin_amdgcn_mfma_f32_16x16x32_f16(
                a2, WF1[((size_t)kt * 4 + t) * 64 + lane], acc2[t], 0, 0, 0);
    }

#pragma unroll
    for (int t = 0; t < 4; ++t) {
        int col = t * 16 + fm;
        float b = bl1[col];
#pragma unroll
        for (int r = 0; r < 4; ++r) {
            int row = tb + g * 4 + r;
            if (row < NN) outp[(size_t)row * COUT + col] = acc2[t][r] + b;
        }
    }
}

// ---------------- CSR gather + BN + ReLU (+residual) ----------------
template <bool RES>
__global__ __launch_bounds__(256) void k_gather(const int* __restrict__ rowptr,
                                                const int* __restrict__ csr,
                                                const float* __restrict__ dinv,
                                                const f16* __restrict__ lin,
                                                const f16* __restrict__ res,
                                                f16* __restrict__ h,
                                                const float* __restrict__ b,
                                                const float* __restrict__ g,
                                                const float* __restrict__ be) {
    const int gw = (blockIdx.x * 256 + threadIdx.x) >> 6;
    const int lane = threadIdx.x & 63;
    if (gw >= NN) return;
    const __half2* lp = (const __half2*)lin;
    // wave-uniform bounds -> scalar loop + uniform csr index stream
    const int start = __builtin_amdgcn_readfirstlane(rowptr[gw]);
    const int end   = __builtin_amdgcn_readfirstlane(rowptr[gw + 1]);

    float2 acc = __half22float2(lp[(size_t)gw * 64 + lane]);  // self term
    int j = start;
    for (; j + 7 < end; j += 8) {
        int s0 = csr[j],     s1 = csr[j + 1], s2 = csr[j + 2], s3 = csr[j + 3];
        int s4 = csr[j + 4], s5 = csr[j + 5], s6 = csr[j + 6], s7 = csr[j + 7];
        float2 v0 = __half22float2(lp[(size_t)s0 * 64 + lane]);
        float2 v1 = __half22float2(lp[(size_t)s1 * 64 + lane]);
        float2 v2 = __half22float2(lp[(size_t)s2 * 64 + lane]);
        float2 v3 = __half22float2(lp[(size_t)s3 * 64 + lane]);
        float2 v4 = __half22float2(lp[(size_t)s4 * 64 + lane]);
        float2 v5 = __half22float2(lp[(size_t)s5 * 64 + lane]);
        float2 v6 = __half22float2(lp[(size_t)s6 * 64 + lane]);
        float2 v7 = __half22float2(lp[(size_t)s7 * 64 + lane]);
        acc.x += ((v0.x + v1.x) + (v2.x + v3.x)) + ((v4.x + v5.x) + (v6.x + v7.x));
        acc.y += ((v0.y + v1.y) + (v2.y + v3.y)) + ((v4.y + v5.y) + (v6.y + v7.y));
    }
    for (; j + 3 < end; j += 4) {
        int s0 = csr[j], s1 = csr[j + 1], s2 = csr[j + 2], s3 = csr[j + 3];
        float2 v0 = __half22float2(lp[(size_t)s0 * 64 + lane]);
        float2 v1 = __half22float2(lp[(size_t)s1 * 64 + lane]);
        float2 v2 = __half22float2(lp[(size_t)s2 * 64 + lane]);
        float2 v3 = __half22float2(lp[(size_t)s3 * 64 + lane]);
        acc.x += (v0.x + v1.x) + (v2.x + v3.x);
        acc.y += (v0.y + v1.y) + (v2.y + v3.y);
    }
    for (; j < end; ++j) {
        int s = csr[j];
        float2 v = __half22float2(lp[(size_t)s * 64 + lane]);
        acc.x += v.x;
        acc.y += v.y;
    }
    const float inv_sqrt = 0.99999500003749968f;  // 1/sqrt(1+1e-5)
    float dv = dinv[gw];
    int f = lane * 2;
    float2 bb = *(const float2*)&b[f];
    float2 gg = *(const float2*)&g[f];
    float2 ee = *(const float2*)&be[f];
    float t0 = fmaxf((acc.x * dv + bb.x) * (gg.x * inv_sqrt) + ee.x, 0.0f);
    float t1 = fmaxf((acc.y * dv + bb.y) * (gg.y * inv_sqrt) + ee.y, 0.0f);
    if (RES) {
        float2 rv = __half22float2(((const __half2*)res)[(size_t)gw * 64 + lane]);
        t0 += rv.x;
        t1 += rv.y;
    }
    ((__half2*)h)[(size_t)gw * 64 + lane] = __floats2half2_rn(t0, t1);
}

// ---------------- pooling ----------------
__global__ void k_count(const int* __restrict__ batch, float* __restrict__ cnt) {
    __shared__ float hist[NB];
    int tid = threadIdx.x;
    if (tid < NB) hist[tid] = 0.0f;
    __syncthreads();
    int n = blockIdx.x * 256 + tid;
    if (n < NN) atomicAdd(&hist[batch[n]], 1.0f);
    __syncthreads();
    if (tid < NB && hist[tid] != 0.0f) atomicAdd(&cnt[tid], hist[tid]);
}

__global__ void k_pool(const f16* __restrict__ h, const int* __restrict__ batch,
                       float* __restrict__ pool) {
    int n0 = blockIdx.x * 64;
    int j = threadIdx.x;
    int cur = batch[n0];
    float acc = 0.0f;
    int nend = (n0 + 64 < NN) ? n0 + 64 : NN;
    for (int n = n0; n < nend; ++n) {
        int b = batch[n];
        if (b != cur) {
            atomicAdd(&pool[cur * CH + j], acc);
            acc = 0.0f;
            cur = b;
        }
        acc += (float)h[(size_t)n * CH + j];
    }
    atomicAdd(&pool[cur * CH + j], acc);
}

__global__ void k_pool_fin(const float* __restrict__ pool,
                           const float* __restrict__ cnt,
                           float* __restrict__ out) {
    int i = blockIdx.x * 256 + threadIdx.x;
    if (i < NB * CH) {
        float c = fmaxf(cnt[i / CH], 1.0f);
        out[i] = pool[i] / c;
    }
}

// ---------------- launch ----------------
extern "C" void kernel_launch(void* const* d_in, const int* in_sizes, int n_in,
                              void* d_out, int out_size, void* d_ws, size_t ws_size,
                              hipStream_t stream) {
    float* outp  = (float*)d_out;                  // [NN, COUT] f32
    float* poolp = outp + (size_t)NN * COUT;       // [NB, CH] f32

    // ---- workspace layout (~84.2 MB; stage aliases rbuf) ----
    const size_t HB = (size_t)NN * CH * 2;         // f16 h          25.6 MB
    const size_t LB = (size_t)NN * CH * 2;         // f16 linscaled  25.6 MB
    const size_t RB = (size_t)NN * CH * 2;         // f16 residual / stage alias
    const size_t DV = (size_t)NN * 4;
    const size_t RP = 400016;                      // (NN+1)*4 padded to 16
    const size_t CS = (size_t)NE * 4;
    const size_t GC = 512;                         // gcur 128 ints
    const size_t BA = 528;                         // barr 128+pad
    const size_t PL = (size_t)NB * CH * 4;
    const size_t CT = 256;
    const size_t F0B = 4096 * 16, F1B = 2048 * 16, FLB = 1024 * 16;
    const size_t need = HB + LB + RB + DV + RP + CS + GC + BA + PL + CT
                        + 2 * F0B + 3 * F1B + FLB;
    if (ws_size < need) {
        k_sentinel<<<(out_size + 255) / 256, 256, 0, stream>>>(outp, out_size, 2000.0f);
        return;
    }
    char* p = (char*)d_ws;
    f16*   hbuf   = (f16*)p;               p += HB;
    f16*   lbuf   = (f16*)p;               p += LB;
    f16*   rbuf   = (f16*)p;
    int*   stage  = (int*)p;               p += RB;   // alias: stage used before rbuf
    float* dinv   = (float*)p;             p += DV;
    int*   rowptr = (int*)p;               p += RP;
    int*   csr    = (int*)p;               p += CS;
    int*   gcur   = (int*)p;               p += GC;
    int*   barr   = (int*)p;               p += BA;
    float* pool   = (float*)p;             p += PL;
    float* cnt    = (float*)p;             p += CT;
    half8* F0     = (half8*)p;             p += F0B;
    half8* Fres   = (half8*)p;             p += F0B;
    half8* F1     = (half8*)p;             p += F1B;
    half8* F2     = (half8*)p;             p += F1B;
    half8* Fl0    = (half8*)p;             p += F1B;
    half8* Fl1    = (half8*)p;

    const float* x   = (const float*)d_in[0];
    const int*   ei  = (const int*)d_in[1];
    const int*   bat = (const int*)d_in[2];
    const float* W0 = (const float*)d_in[3],  *b0 = (const float*)d_in[4];
    const float* W1 = (const float*)d_in[5],  *b1 = (const float*)d_in[6];
    const float* W2 = (const float*)d_in[7],  *b2 = (const float*)d_in[8];
    const float* g0 = (const float*)d_in[9],  *be0 = (const float*)d_in[10];
    const float* g1 = (const float*)d_in[11], *be1 = (const float*)d_in[12];
    const float* g2 = (const float*)d_in[13], *be2 = (const float*)d_in[14];
    const float* Wres = (const float*)d_in[15], *bres = (const float*)d_in[16];
    const float* Wl0 = (const float*)d_in[17], *bl0 = (const float*)d_in[18];
    const float* Wl1 = (const float*)d_in[19], *bl1 = (const float*)d_in[20];

    const int* src = ei;
    const int* dst = ei + NE;

    const int gRow = (NN + 63) / 64;              // 1563
    const int gGat = (NN * 64) / 256;             // 25000

    // ---- CSR build: bin -> bucket scan -> per-bucket CSR/rowptr/dinv ----
    k_init<<<33, 256, 0, stream>>>(pool, cnt, gcur);
    k_wconv<<<60, 256, 0, stream>>>(W0, Wres, W1, W2, Wl0, Wl1,
                                    F0, Fres, F1, F2, Fl0, Fl1);
    k_bin<<<G1, 256, 0, stream>>>(src, dst, gcur, stage);
    k_gtot<<<1, 64, 0, stream>>>(gcur, barr, rowptr);
    k_csr<<<NBUK, 256, 0, stream>>>(gcur, barr, stage, rowptr, csr, dinv);

    // ---- layer 0 fused with residual: LDS-staged A+B, 2-phase pipeline ----
    k_mfma0<<<gRow, 256, 0, stream>>>(x, F0, Fres, bres, dinv, lbuf, rbuf);
    k_gather<true><<<gGat, 256, 0, stream>>>(rowptr, csr, dinv, lbuf, rbuf, hbuf, b0, g0, be0);

    // ---- layer 1 (barrier-free f16 GEMM) ----
    k_lin<<<gRow, 256, 0, stream>>>(hbuf, F1, dinv, lbuf);
    k_gather<false><<<gGat, 256, 0, stream>>>(rowptr, csr, dinv, lbuf, nullptr, hbuf, b1, g1, be1);

    // ---- layer 2 ----
    k_lin<<<gRow, 256, 0, stream>>>(hbuf, F2, dinv, lbuf);
    k_gather<false><<<gGat, 256, 0, stream>>>(rowptr, csr, dinv, lbuf, nullptr, hbuf, b2, g2, be2);

    // ---- mean pool over graphs (final h) ----
    k_count<<<(NN + 255) / 256, 256, 0, stream>>>(bat, cnt);
    k_pool<<<gRow, 128, 0, stream>>>(hbuf, bat, pool);
    k_pool_fin<<<(NB * CH + 255) / 256, 256, 0, stream>>>(pool, cnt, poolp);

    // ---- fused head MLP ----
    k_head<<<gRow, 256, 0, stream>>>(hbuf, Fl0, Fl1, bl0, bl1, outp);
}